// Round 12
// baseline (110.011 us; speedup 1.0000x reference)
//
#include <hip/hip_runtime.h>
#include <stdint.h>

#define NPIX 9216   // 96*96
#define NIMG 32
#define STRIP 1152  // NPIX / 8 strips

// ---------- JAX threefry2x32 (20 rounds), bit-exact (verified rounds 1-11) ----------
__device__ __forceinline__ uint32_t rotl32(uint32_t x, int d){ return (x<<d)|(x>>(32-d)); }

__device__ __forceinline__ void threefry(uint32_t k0, uint32_t k1, uint32_t x0, uint32_t x1,
                                         uint32_t &o0, uint32_t &o1){
  uint32_t ks2 = k0 ^ k1 ^ 0x1BD11BDAu;
  x0 += k0; x1 += k1;
  x0+=x1; x1=rotl32(x1,13); x1^=x0;
  x0+=x1; x1=rotl32(x1,15); x1^=x0;
  x0+=x1; x1=rotl32(x1,26); x1^=x0;
  x0+=x1; x1=rotl32(x1,6);  x1^=x0;
  x0+=k1; x1+=ks2+1u;
  x0+=x1; x1=rotl32(x1,17); x1^=x0;
  x0+=x1; x1=rotl32(x1,29); x1^=x0;
  x0+=x1; x1=rotl32(x1,16); x1^=x0;
  x0+=x1; x1=rotl32(x1,24); x1^=x0;
  x0+=ks2; x1+=k0+2u;
  x0+=x1; x1=rotl32(x1,13); x1^=x0;
  x0+=x1; x1=rotl32(x1,15); x1^=x0;
  x0+=x1; x1=rotl32(x1,26); x1^=x0;
  x0+=x1; x1=rotl32(x1,6);  x1^=x0;
  x0+=k0; x1+=k1+3u;
  x0+=x1; x1=rotl32(x1,17); x1^=x0;
  x0+=x1; x1=rotl32(x1,29); x1^=x0;
  x0+=x1; x1=rotl32(x1,16); x1^=x0;
  x0+=x1; x1=rotl32(x1,24); x1^=x0;
  x0+=k1; x1+=ks2+4u;
  x0+=x1; x1=rotl32(x1,13); x1^=x0;
  x0+=x1; x1=rotl32(x1,15); x1^=x0;
  x0+=x1; x1=rotl32(x1,26); x1^=x0;
  x0+=x1; x1=rotl32(x1,6);  x1^=x0;
  x0+=ks2; x1+=k0+5u;
  o0=x0; o1=x1;
}

__device__ __forceinline__ float clip01_div255(float x){
  return fminf(fmaxf(x/255.0f, 0.0f), 1.0f);
}

// ---------- K1: 256 blocks = img x 8 strips. Redundant full-image channel max
// (12-float groups, fixed channel map — R8-verified math), then BOTH classes
// scored per strip (fg mask computed once, reused); exact local top-50 per class. --
__global__ __launch_bounds__(256) void kscore(const float* __restrict__ in,
                                              unsigned long long* __restrict__ key50g){
#pragma clang fp contract(off)
  int b   = blockIdx.x;                 // img*8 + sub
  int img = b >> 3, sub = b & 7;
  int tid = threadIdx.x;
  int lane = tid & 63, wv = tid >> 6;

  __shared__ __attribute__((aligned(16))) float pixL[3456];  // strip pixels
  __shared__ uint32_t vvL[STRIP];
  __shared__ uint64_t cand[STRIP];
  __shared__ unsigned char fgm[STRIP];
  __shared__ int hist[129];
  __shared__ int ncand, bbin;
  __shared__ float red[3][4];

  const float* p = in + (size_t)img*NPIX*3;

  // stage own strip (864 float4, coalesced)
  const float4* sp4 = (const float4*)(p + (size_t)sub*STRIP*3);
  float4* pixL4 = (float4*)pixL;
  for(int k=0;k<4;k++){ int i4=k*256+tid; if(i4<864) pixL4[i4]=sp4[i4]; }

  // redundant full-image channel max: 2304 groups of 3 float4 (= 4 pixels),
  // fixed channel map v0=(0,1,2,0) v1=(1,2,0,1) v2=(2,0,1,2); fmax exactly assoc.
  float m0=0.f,m1=0.f,m2=0.f;
  const float4* p4 = (const float4*)p;
#pragma unroll 3
  for(int k=0;k<9;k++){
    int g = tid + k*256;
    float4 v0=p4[3*g], v1=p4[3*g+1], v2=p4[3*g+2];
    m0=fmaxf(m0, fmaxf(fmaxf(clip01_div255(v0.x),clip01_div255(v0.w)),
                       fmaxf(clip01_div255(v1.z),clip01_div255(v2.y))));
    m1=fmaxf(m1, fmaxf(fmaxf(clip01_div255(v0.y),clip01_div255(v1.x)),
                       fmaxf(clip01_div255(v1.w),clip01_div255(v2.z))));
    m2=fmaxf(m2, fmaxf(fmaxf(clip01_div255(v0.z),clip01_div255(v1.y)),
                       fmaxf(clip01_div255(v2.x),clip01_div255(v2.w))));
  }
  for(int off=32;off>0;off>>=1){
    m0=fmaxf(m0,__shfl_down(m0,off));
    m1=fmaxf(m1,__shfl_down(m1,off));
    m2=fmaxf(m2,__shfl_down(m2,off));
  }
  if(lane==0){ red[0][wv]=m0; red[1][wv]=m1; red[2][wv]=m2; }
  __syncthreads();
  float c0=fmaxf(fmaxf(red[0][0],red[0][1]),fmaxf(red[0][2],red[0][3]));
  float c1=fmaxf(fmaxf(red[1][0],red[1][1]),fmaxf(red[1][2],red[1][3]));
  float c2=fmaxf(fmaxf(red[2][0],red[2][1]),fmaxf(red[2][2],red[2][3]));

  // partitionable threefry image key (bit-exact)
  uint32_t ik0, ik1; threefry(0u, 42u, 0u, (uint32_t)img, ik0, ik1);

  for(int cls=0; cls<2; cls++){
    __syncthreads();                     // prior phase (staging max / cls0 rank) done
    if(tid<129) hist[tid]=0;
    if(tid==0)  ncand=0;
    uint32_t s0, s1; threefry(ik0, ik1, 0u, (uint32_t)cls, s0, s1);
    __syncthreads();

    // score strip + histogram (math bit-identical to rounds 6-11)
    for(int r=0;r<5;r++){
      int pi = tid + r*256;
      if(pi<STRIP){
        bool valid;
        if(cls==0){
          float a  = clip01_div255(pixL[pi*3+0])/c0;
          float bb = clip01_div255(pixL[pi*3+1])/c1;
          float c  = clip01_div255(pixL[pi*3+2])/c2;
          bool fg = (a>0.f && a<0.6f) || (bb>0.f && bb<0.6f) || (c>0.f && c<0.6f);
          fgm[pi] = fg ? 1 : 0;
          valid = fg;
        } else {
          valid = (fgm[pi] == 0);
        }
        uint32_t gi = (uint32_t)(sub*STRIP + pi);
        uint32_t r1,r2; threefry(s0, s1, 0u, gi, r1, r2);
        uint32_t vv = valid ? ((r1 ^ r2) >> 9) + 1u : 0u;  // monotone; 0 = invalid(-1.0)
        vvL[pi] = vv;
        atomicAdd(&hist[vv>>16], 1);
      }
    }
    __syncthreads();

    // bbin = largest bin with suffix-count >= 50 (R11-verified wave scan)
    if(tid < 64){
      int h0 = hist[2*tid];
      int h1 = hist[2*tid+1];
      int h128 = hist[128];
      int S = h0 + h1;
      for(int off=1; off<64; off<<=1){
        int o = __shfl_down(S, off);
        if(tid + off < 64) S += o;
      }
      int ss0 = S + h128;
      int ss1 = S - h0 + h128;
      int cd = -1;
      if(ss0 >= 50) cd = 2*tid;
      if(ss1 >= 50) cd = 2*tid+1;
      if(tid==63 && h128 >= 50) cd = 128;
      for(int off=32; off>0; off>>=1){
        int o = __shfl_down(cd, off);
        cd = o > cd ? o : cd;
      }
      if(tid==0) bbin = cd;              // ss(0)=1152>=50 -> cd>=0 guaranteed
    }
    __syncthreads();

    int bb = bbin;
    for(int r=0;r<5;r++){
      int pi = tid + r*256;
      if(pi<STRIP){
        uint32_t vv = vvL[pi];
        if((int)(vv>>16) >= bb){
          int pos = atomicAdd(&ncand,1);
          cand[pos] = ((uint64_t)vv << 14) | (uint64_t)(16383 - (sub*STRIP + pi));
        }
      }
    }
    __syncthreads();
    int m = ncand;
    for(int c=tid;c<m;c+=256){
      uint64_t k = cand[c];
      int r = 0, j = 0;
      while(j < m){                      // chunked early-exit: exact for r<50
        int je = j+64 < m ? j+64 : m;
        for(; j<je; j++) r += (cand[j] > k);
        if(r >= 50) break;
      }
      if(r < 50) key50g[(size_t)(img*16 + cls*8 + sub)*50 + r] = k;
    }
  }
}

// ---------- K2 (32 blocks): merge 16 strip lists -> top-50/class -> stats ->
// pair-interleaved pack: pair p holds rows (2p,2p+1) as (f0.x f0.y f1.x f1.y ... pad2)
__global__ __launch_bounds__(256) void kmerge(const float* __restrict__ in,
                                              const unsigned long long* __restrict__ key50g,
                                              float* __restrict__ ts2g,      // [32][600]
                                              float* __restrict__ meanstd){  // [32][10]
#pragma clang fp contract(off)
  int img = blockIdx.x;
  int tid = threadIdx.x;
  __shared__ uint64_t kk[800];
  __shared__ int      tIdx[100];
  __shared__ float    feat[100][5];
  __shared__ float    mv[5], sv[5];

  const uint64_t* kg = (const uint64_t*)key50g + (size_t)img*800;
  for(int c=tid;c<800;c+=256) kk[c] = kg[c];
  __syncthreads();

  // global rank within class via binary search on 8 descending 50-lists (keys unique)
  for(int c=tid;c<800;c+=256){
    uint64_t k = kk[c];
    int cl = (c >= 400);
    int base = cl*400;
    int r = 0;
#pragma unroll
    for(int s=0;s<8;s++){
      const uint64_t* L = &kk[base + s*50];
      int lo=0, hi=50;
      while(lo<hi){ int mid=(lo+hi)>>1; if(L[mid] > k) lo=mid+1; else hi=mid; }
      r += lo;
    }
    if(r < 50) tIdx[cl*50+r] = 16383 - (int)(k & 16383u);
  }
  __syncthreads();

  // train features + stats (math bit-identical to rounds 1-11)
  if(tid<100){
    int pp = tIdx[tid];
    int i=pp/96, j=pp-i*96;
    const float* px = in + ((size_t)img*NPIX + pp)*3;
    for(int c=0;c<3;c++){
      float ip=clip01_div255(px[c]);
      feat[tid][c]=ip/255.0f;
    }
    feat[tid][3]=((float)i/96.0f)*100.0f;
    feat[tid][4]=((float)j/96.0f)*100.0f;
  }
  __syncthreads();
  if(tid<5){
    float s=0.f;
    for(int r=0;r<100;r++) s=s+feat[r][tid];
    float mu=s/100.0f; mv[tid]=mu;
    float v=0.f;
    for(int r=0;r<100;r++){ float d=feat[r][tid]-mu; float q=d*d; v=v+q; }
    sv[tid]=sqrtf(v/100.0f);
  }
  __syncthreads();
  // pair-interleaved layout: f_k of row r at [pair*12 + 2k + (r&1)], pair=r>>1
  if(tid<100){
    float r0=(feat[tid][0]-mv[0])/sv[0];
    float r1=(feat[tid][1]-mv[1])/sv[1];
    float r2=(feat[tid][2]-mv[2])/sv[2];
    float r3=(feat[tid][3]-mv[3])/sv[3];
    float r4=(feat[tid][4]-mv[4])/sv[4];
    float* dst = ts2g + img*600 + (tid>>1)*12 + (tid&1);
    dst[0]=r0; dst[2]=r1; dst[4]=r2; dst[6]=r3; dst[8]=r4;
  }
  if(tid<5)       meanstd[img*10+tid]=mv[tid];
  else if(tid<10) meanstd[img*10+tid]=sv[tid-5];
}

// ---------- K3: 1152 blocks: 5-NN with packed-pair min/max insertion networks ------
__global__ __launch_bounds__(256) void kknn(const float* __restrict__ in,
                                            const float* __restrict__ ts2g,
                                            const float* __restrict__ meanstd,
                                            float* __restrict__ out){
#pragma clang fp contract(off)
  int b     = blockIdx.x;
  int img   = b / 36;
  int chunk = b % 36;
  int tid   = threadIdx.x;

  __shared__ float    mv[5], sv[5];
  __shared__ __attribute__((aligned(16))) float ts2[600];  // pair-interleaved rows
  __shared__ __attribute__((aligned(16))) float pix[768];

  if(tid<150) ((float4*)ts2)[tid] = ((const float4*)(ts2g + img*600))[tid];
  if(tid>=192 && tid<197) mv[tid-192]=meanstd[img*10+(tid-192)];
  if(tid>=224 && tid<229) sv[tid-224]=meanstd[img*10+5+(tid-224)];
  {
    const float4* cb4 = (const float4*)(in + ((size_t)img*NPIX + (size_t)chunk*256)*3);
    if(tid<192) ((float4*)pix)[tid] = cb4[tid];
  }
  __syncthreads();

  // test feature for own pixel (bit-identical math)
  int p = chunk*256+tid;
  int i=p/96, j=p-i*96;
  float ip0=clip01_div255(pix[tid*3+0]);
  float ip1=clip01_div255(pix[tid*3+1]);
  float ip2=clip01_div255(pix[tid*3+2]);
  float t0,t1,t2,t3,t4;
  {
    float f0=ip0/255.0f, f1=ip1/255.0f, f2=ip2/255.0f;
    float f3=((float)i/96.0f)*100.0f, f4=((float)j/96.0f)*100.0f;
    t0=(f0-mv[0])/sv[0]; t1=(f1-mv[1])/sv[1]; t2=(f2-mv[2])/sv[2];
    t3=(f3-mv[3])/sv[3]; t4=(f4-mv[4])/sv[4];
  }

  // fg pairs 0..24 (rows 0..49): packed top-2 via min/max insertion network.
  // .x = even-row chain, .y = odd-row chain; per-row d^2 op order identical to R6-11;
  // value-only selection via min/max networks is exact (same multiset).
  float a0x=1e30f,a0y=1e30f, a1x=1e30f,a1y=1e30f;
#pragma unroll 5
  for(int pr=0;pr<25;pr++){
    const float* tp = &ts2[pr*12];
    float4 qA = *(const float4*)(tp);    // f0(x,y) f1(x,y)
    float4 qB = *(const float4*)(tp+4);  // f2(x,y) f3(x,y)
    float2 qC = *(const float2*)(tp+8);  // f4(x,y)
    float sx, sy;
    { float dx=t0-qA.x, dy=t0-qA.y; sx=dx*dx; sy=dy*dy; }
    { float dx=t1-qA.z, dy=t1-qA.w; float wx=dx*dx, wy=dy*dy; sx=sx+wx; sy=sy+wy; }
    { float dx=t2-qB.x, dy=t2-qB.y; float wx=dx*dx, wy=dy*dy; sx=sx+wx; sy=sy+wy; }
    { float dx=t3-qB.z, dy=t3-qB.w; float wx=dx*dx, wy=dy*dy; sx=sx+wx; sy=sy+wy; }
    { float dx=t4-qC.x, dy=t4-qC.y; float wx=dx*dx, wy=dy*dy; sx=sx+wx; sy=sy+wy; }
    float tx=fmaxf(a0x,sx), ty=fmaxf(a0y,sy);
    a0x=fminf(a0x,sx);      a0y=fminf(a0y,sy);
    a1x=fminf(a1x,tx);      a1y=fminf(a1y,ty);
  }
  // exact 2nd-smallest of union of the two sorted pairs (bitonic split)
  float a1 = fmaxf(fminf(a0x,a1y), fminf(a1x,a0y));

  // bg pairs 25..49 (rows 50..99): packed top-4 insertion network
  float b0x=1e30f,b0y=1e30f, b1x=1e30f,b1y=1e30f;
  float b2x=1e30f,b2y=1e30f, b3x=1e30f,b3y=1e30f;
#pragma unroll 5
  for(int pr=25;pr<50;pr++){
    const float* tp = &ts2[pr*12];
    float4 qA = *(const float4*)(tp);
    float4 qB = *(const float4*)(tp+4);
    float2 qC = *(const float2*)(tp+8);
    float sx, sy;
    { float dx=t0-qA.x, dy=t0-qA.y; sx=dx*dx; sy=dy*dy; }
    { float dx=t1-qA.z, dy=t1-qA.w; float wx=dx*dx, wy=dy*dy; sx=sx+wx; sy=sy+wy; }
    { float dx=t2-qB.x, dy=t2-qB.y; float wx=dx*dx, wy=dy*dy; sx=sx+wx; sy=sy+wy; }
    { float dx=t3-qB.z, dy=t3-qB.w; float wx=dx*dx, wy=dy*dy; sx=sx+wx; sy=sy+wy; }
    { float dx=t4-qC.x, dy=t4-qC.y; float wx=dx*dx, wy=dy*dy; sx=sx+wx; sy=sy+wy; }
    float u0x=fmaxf(b0x,sx), u0y=fmaxf(b0y,sy);
    b0x=fminf(b0x,sx);       b0y=fminf(b0y,sy);
    float u1x=fmaxf(b1x,u0x), u1y=fmaxf(b1y,u0y);
    b1x=fminf(b1x,u0x);       b1y=fminf(b1y,u0y);
    float u2x=fmaxf(b2x,u1x), u2y=fmaxf(b2y,u1y);
    b2x=fminf(b2x,u1x);       b2y=fminf(b2y,u1y);
    b3x=fminf(b3x,u2x);       b3y=fminf(b3y,u2y);
  }
  // exact 4th-smallest of union of two sorted quads (bitonic lower-half merge)
  float l0=fminf(b0x,b3y), l1=fminf(b1x,b2y), l2=fminf(b2x,b1y), l3=fminf(b3x,b0y);
  float b3 = fmaxf(fmaxf(l0,l1), fmaxf(l2,l3));

  // seg <=> 2nd-smallest fg sqrt-dist <= 4th-smallest bg sqrt-dist (fg wins ties)
  bool seg = sqrtf(a1) <= sqrtf(b3);
  __syncthreads();                       // pix reuse fence
  pix[tid*3+0]=seg?ip0:0.f;
  pix[tid*3+1]=seg?ip1:0.f;
  pix[tid*3+2]=seg?ip2:0.f;
  __syncthreads();
  float4* ob4 = (float4*)(out + ((size_t)img*NPIX + (size_t)chunk*256)*3);
  if(tid<192) ob4[tid] = ((float4*)pix)[tid];
}

extern "C" void kernel_launch(void* const* d_in, const int* in_sizes, int n_in,
                              void* d_out, int out_size, void* d_ws, size_t ws_size,
                              hipStream_t stream) {
  const float* in = (const float*)d_in[0];
  float* out = (float*)d_out;
  unsigned long long* key50g = (unsigned long long*)d_ws;   // 512*50*8 = 204800 B
  float* ts2g    = (float*)((char*)d_ws + 204800);          // 76800 B
  float* meanstd = (float*)((char*)d_ws + 281600);          // 1280 B

  kscore<<<256,  256, 0, stream>>>(in, key50g);
  kmerge<<<32,   256, 0, stream>>>(in, key50g, ts2g, meanstd);
  kknn  <<<1152, 256, 0, stream>>>(in, ts2g, meanstd, out);
}

// Round 13
// 103.707 us; speedup vs baseline: 1.0608x; 1.0608x over previous
//
#include <hip/hip_runtime.h>
#include <stdint.h>

#define NPIX 9216   // 96*96
#define NIMG 32
#define STRIP 1152  // NPIX / 8 strips

// ---------- JAX threefry2x32 (20 rounds), bit-exact (verified rounds 1-12) ----------
__device__ __forceinline__ uint32_t rotl32(uint32_t x, int d){ return (x<<d)|(x>>(32-d)); }

__device__ __forceinline__ void threefry(uint32_t k0, uint32_t k1, uint32_t x0, uint32_t x1,
                                         uint32_t &o0, uint32_t &o1){
  uint32_t ks2 = k0 ^ k1 ^ 0x1BD11BDAu;
  x0 += k0; x1 += k1;
  x0+=x1; x1=rotl32(x1,13); x1^=x0;
  x0+=x1; x1=rotl32(x1,15); x1^=x0;
  x0+=x1; x1=rotl32(x1,26); x1^=x0;
  x0+=x1; x1=rotl32(x1,6);  x1^=x0;
  x0+=k1; x1+=ks2+1u;
  x0+=x1; x1=rotl32(x1,17); x1^=x0;
  x0+=x1; x1=rotl32(x1,29); x1^=x0;
  x0+=x1; x1=rotl32(x1,16); x1^=x0;
  x0+=x1; x1=rotl32(x1,24); x1^=x0;
  x0+=ks2; x1+=k0+2u;
  x0+=x1; x1=rotl32(x1,13); x1^=x0;
  x0+=x1; x1=rotl32(x1,15); x1^=x0;
  x0+=x1; x1=rotl32(x1,26); x1^=x0;
  x0+=x1; x1=rotl32(x1,6);  x1^=x0;
  x0+=k0; x1+=k1+3u;
  x0+=x1; x1=rotl32(x1,17); x1^=x0;
  x0+=x1; x1=rotl32(x1,29); x1^=x0;
  x0+=x1; x1=rotl32(x1,16); x1^=x0;
  x0+=x1; x1=rotl32(x1,24); x1^=x0;
  x0+=k1; x1+=ks2+4u;
  x0+=x1; x1=rotl32(x1,13); x1^=x0;
  x0+=x1; x1=rotl32(x1,15); x1^=x0;
  x0+=x1; x1=rotl32(x1,26); x1^=x0;
  x0+=x1; x1=rotl32(x1,6);  x1^=x0;
  x0+=ks2; x1+=k0+5u;
  o0=x0; o1=x1;
}

__device__ __forceinline__ float clip01_div255(float x){
  return fminf(fmaxf(x/255.0f, 0.0f), 1.0f);
}

// ---------- K0: partial channel max, 6 blocks/image (reads image exactly once) -----
__global__ __launch_bounds__(256) void kmax(const float* __restrict__ in,
                                            float* __restrict__ maxpart){
  int img  = blockIdx.x / 6;
  int part = blockIdx.x % 6;
  int tid  = threadIdx.x;
  const float* base = in + (size_t)img*NPIX*3 + (size_t)part*1536*3;
  float m0=0.f, m1=0.f, m2=0.f;
#pragma unroll
  for(int k=0;k<18;k++){
    int g = k*256 + tid;
    float v = clip01_div255(base[g]);
    int c = g % 3;
    m0 = (c==0) ? fmaxf(m0,v) : m0;
    m1 = (c==1) ? fmaxf(m1,v) : m1;
    m2 = (c==2) ? fmaxf(m2,v) : m2;
  }
  for(int off=32; off>0; off>>=1){
    m0 = fmaxf(m0, __shfl_down(m0,off));
    m1 = fmaxf(m1, __shfl_down(m1,off));
    m2 = fmaxf(m2, __shfl_down(m2,off));
  }
  __shared__ float r[3][4];
  int lane = tid & 63, wv = tid >> 6;
  if(lane==0){ r[0][wv]=m0; r[1][wv]=m1; r[2][wv]=m2; }
  __syncthreads();
  if(tid==0){
    maxpart[blockIdx.x*3+0]=fmaxf(fmaxf(r[0][0],r[0][1]),fmaxf(r[0][2],r[0][3]));
    maxpart[blockIdx.x*3+1]=fmaxf(fmaxf(r[1][0],r[1][1]),fmaxf(r[1][2],r[1][3]));
    maxpart[blockIdx.x*3+2]=fmaxf(fmaxf(r[2][0],r[2][1]),fmaxf(r[2][2],r[2][3]));
  }
}

// ---------- K1: 512 blocks = img x cls x 8 strips (R7/R11-verified structure).
// LDS staging, VALID-ONLY histogram (kills hist[0] same-address atomic storm),
// exact local top-50; bbin via single-wave shfl suffix scan. ----------
__global__ __launch_bounds__(256) void kscore(const float* __restrict__ in,
                                              const float* __restrict__ maxpart,
                                              unsigned long long* __restrict__ key50g){
#pragma clang fp contract(off)
  int b   = blockIdx.x;                 // img*16 + cls*8 + sub
  int img = b >> 4, cls = (b >> 3) & 1, sub = b & 7;
  int tid = threadIdx.x;

  __shared__ __attribute__((aligned(16))) float pixL[3456];  // strip pixels
  __shared__ uint32_t vvL[STRIP];
  __shared__ uint64_t cand[STRIP];
  __shared__ int hist[129];
  __shared__ int ncand, bbin;

  if(tid<129) hist[tid]=0;
  if(tid==0)  ncand=0;

  const float* p = in + (size_t)img*NPIX*3;

  // stage own strip (864 float4, coalesced)
  const float4* sp4 = (const float4*)(p + (size_t)sub*STRIP*3);
  float4* pixL4 = (float4*)pixL;
  for(int k=0;k<4;k++){ int i4=k*256+tid; if(i4<864) pixL4[i4]=sp4[i4]; }

  // fold 6 partial maxes (uniform -> scalar loads; fmax exactly associative)
  float c0=0.f,c1=0.f,c2=0.f;
#pragma unroll
  for(int s=0;s<6;s++){
    c0=fmaxf(c0, maxpart[(img*6+s)*3+0]);
    c1=fmaxf(c1, maxpart[(img*6+s)*3+1]);
    c2=fmaxf(c2, maxpart[(img*6+s)*3+2]);
  }

  // partitionable threefry keys (bit-exact)
  uint32_t ik0, ik1; threefry(0u, 42u, 0u, (uint32_t)img, ik0, ik1);
  uint32_t s0, s1;   threefry(ik0, ik1, 0u, (uint32_t)cls, s0, s1);
  __syncthreads();

  // score strip + histogram (math bit-identical to rounds 6-12); valid-only adds
  for(int r=0;r<5;r++){
    int pi = tid + r*256;
    if(pi<STRIP){
      float a  = clip01_div255(pixL[pi*3+0])/c0;
      float bb = clip01_div255(pixL[pi*3+1])/c1;
      float c  = clip01_div255(pixL[pi*3+2])/c2;
      bool fg = (a>0.f && a<0.6f) || (bb>0.f && bb<0.6f) || (c>0.f && c<0.6f);
      bool valid = (cls==0) ? fg : !fg;
      uint32_t gi = (uint32_t)(sub*STRIP + pi);
      uint32_t r1,r2; threefry(s0, s1, 0u, gi, r1, r2);
      uint32_t vv = valid ? ((r1 ^ r2) >> 9) + 1u : 0u;  // monotone in uniform; 0 = invalid(-1.0)
      vvL[pi] = vv;
      if(vv) atomicAdd(&hist[vv>>16], 1);   // hist[0] never counted (would be the
    }                                        // 64-lane same-address storm)
  }
  __syncthreads();

  // bbin = largest bin with suffix-count >= 50 (R11-verified wave scan).
  // If <50 valid keys in strip: cd stays -1 -> every key (incl. invalid, which sort
  // by ascending index after all valid -- matching top_k of -1.0 ties) is a candidate.
  if(tid < 64){
    int h0 = hist[2*tid];
    int h1 = hist[2*tid+1];
    int h128 = hist[128];
    int S = h0 + h1;
    for(int off=1; off<64; off<<=1){
      int o = __shfl_down(S, off);
      if(tid + off < 64) S += o;
    }
    int ss0 = S + h128;
    int ss1 = S - h0 + h128;
    int cd = -1;
    if(ss0 >= 50) cd = 2*tid;
    if(ss1 >= 50) cd = 2*tid+1;
    if(tid==63 && h128 >= 50) cd = 128;
    for(int off=32; off>0; off>>=1){
      int o = __shfl_down(cd, off);
      cd = o > cd ? o : cd;
    }
    if(tid==0) bbin = cd;
  }
  __syncthreads();

  int bb = bbin;
  for(int r=0;r<5;r++){
    int pi = tid + r*256;
    if(pi<STRIP){
      uint32_t vv = vvL[pi];
      if((int)(vv>>16) >= bb){
        int pos = atomicAdd(&ncand,1);
        cand[pos] = ((uint64_t)vv << 14) | (uint64_t)(16383 - (sub*STRIP + pi));  // higher = earlier
      }
    }
  }
  __syncthreads();
  int m = ncand;
  for(int c=tid;c<m;c+=256){
    uint64_t k = cand[c];
    int r = 0, j = 0;
    while(j < m){                        // chunked early-exit: exact for r<50
      int je = j+64 < m ? j+64 : m;
      for(; j<je; j++) r += (cand[j] > k);
      if(r >= 50) break;
    }
    if(r < 50) key50g[(size_t)b*50 + r] = k;  // rank r -> descending sorted list
  }
}

// ---------- K2 (32 blocks): merge 16 strip lists -> top-50/class -> stats ->
// pair-interleaved pack (R12-verified): f_k of row r at [pair*12 + 2k + (r&1)] ------
__global__ __launch_bounds__(256) void kmerge(const float* __restrict__ in,
                                              const unsigned long long* __restrict__ key50g,
                                              float* __restrict__ ts2g,      // [32][600]
                                              float* __restrict__ meanstd){  // [32][10]
#pragma clang fp contract(off)
  int img = blockIdx.x;
  int tid = threadIdx.x;
  __shared__ uint64_t kk[800];
  __shared__ int      tIdx[100];
  __shared__ float    feat[100][5];
  __shared__ float    mv[5], sv[5];

  const uint64_t* kg = (const uint64_t*)key50g + (size_t)img*800;
  for(int c=tid;c<800;c+=256) kk[c] = kg[c];
  __syncthreads();

  // global rank within class via binary search on 8 descending 50-lists (keys unique)
  for(int c=tid;c<800;c+=256){
    uint64_t k = kk[c];
    int cl = (c >= 400);
    int base = cl*400;
    int r = 0;
#pragma unroll
    for(int s=0;s<8;s++){
      const uint64_t* L = &kk[base + s*50];
      int lo=0, hi=50;
      while(lo<hi){ int mid=(lo+hi)>>1; if(L[mid] > k) lo=mid+1; else hi=mid; }
      r += lo;
    }
    if(r < 50) tIdx[cl*50+r] = 16383 - (int)(k & 16383u);
  }
  __syncthreads();

  // train features + stats (math bit-identical to rounds 1-12)
  if(tid<100){
    int pp = tIdx[tid];
    int i=pp/96, j=pp-i*96;
    const float* px = in + ((size_t)img*NPIX + pp)*3;
    for(int c=0;c<3;c++){
      float ip=clip01_div255(px[c]);
      feat[tid][c]=ip/255.0f;
    }
    feat[tid][3]=((float)i/96.0f)*100.0f;
    feat[tid][4]=((float)j/96.0f)*100.0f;
  }
  __syncthreads();
  if(tid<5){
    float s=0.f;
    for(int r=0;r<100;r++) s=s+feat[r][tid];
    float mu=s/100.0f; mv[tid]=mu;
    float v=0.f;
    for(int r=0;r<100;r++){ float d=feat[r][tid]-mu; float q=d*d; v=v+q; }
    sv[tid]=sqrtf(v/100.0f);
  }
  __syncthreads();
  // pair-interleaved layout: f_k of row r at [pair*12 + 2k + (r&1)], pair=r>>1
  if(tid<100){
    float r0=(feat[tid][0]-mv[0])/sv[0];
    float r1=(feat[tid][1]-mv[1])/sv[1];
    float r2=(feat[tid][2]-mv[2])/sv[2];
    float r3=(feat[tid][3]-mv[3])/sv[3];
    float r4=(feat[tid][4]-mv[4])/sv[4];
    float* dst = ts2g + img*600 + (tid>>1)*12 + (tid&1);
    dst[0]=r0; dst[2]=r1; dst[4]=r2; dst[6]=r3; dst[8]=r4;
  }
  if(tid<5)       meanstd[img*10+tid]=mv[tid];
  else if(tid<10) meanstd[img*10+tid]=sv[tid-5];
}

// ---------- K3: 1152 blocks: 5-NN, packed-pair min/max insertion networks (R12) ----
__global__ __launch_bounds__(256) void kknn(const float* __restrict__ in,
                                            const float* __restrict__ ts2g,
                                            const float* __restrict__ meanstd,
                                            float* __restrict__ out){
#pragma clang fp contract(off)
  int b     = blockIdx.x;
  int img   = b / 36;
  int chunk = b % 36;
  int tid   = threadIdx.x;

  __shared__ float    mv[5], sv[5];
  __shared__ __attribute__((aligned(16))) float ts2[600];  // pair-interleaved rows
  __shared__ __attribute__((aligned(16))) float pix[768];

  if(tid<150) ((float4*)ts2)[tid] = ((const float4*)(ts2g + img*600))[tid];
  if(tid>=192 && tid<197) mv[tid-192]=meanstd[img*10+(tid-192)];
  if(tid>=224 && tid<229) sv[tid-224]=meanstd[img*10+5+(tid-224)];
  {
    const float4* cb4 = (const float4*)(in + ((size_t)img*NPIX + (size_t)chunk*256)*3);
    if(tid<192) ((float4*)pix)[tid] = cb4[tid];
  }
  __syncthreads();

  // test feature for own pixel (bit-identical math)
  int p = chunk*256+tid;
  int i=p/96, j=p-i*96;
  float ip0=clip01_div255(pix[tid*3+0]);
  float ip1=clip01_div255(pix[tid*3+1]);
  float ip2=clip01_div255(pix[tid*3+2]);
  float t0,t1,t2,t3,t4;
  {
    float f0=ip0/255.0f, f1=ip1/255.0f, f2=ip2/255.0f;
    float f3=((float)i/96.0f)*100.0f, f4=((float)j/96.0f)*100.0f;
    t0=(f0-mv[0])/sv[0]; t1=(f1-mv[1])/sv[1]; t2=(f2-mv[2])/sv[2];
    t3=(f3-mv[3])/sv[3]; t4=(f4-mv[4])/sv[4];
  }

  // fg pairs 0..24 (rows 0..49): packed top-2 via min/max insertion network.
  // .x = even-row chain, .y = odd-row chain; per-row d^2 op order identical to R6-12;
  // value-only selection via min/max networks is exact (same multiset).
  float a0x=1e30f,a0y=1e30f, a1x=1e30f,a1y=1e30f;
#pragma unroll 5
  for(int pr=0;pr<25;pr++){
    const float* tp = &ts2[pr*12];
    float4 qA = *(const float4*)(tp);    // f0(x,y) f1(x,y)
    float4 qB = *(const float4*)(tp+4);  // f2(x,y) f3(x,y)
    float2 qC = *(const float2*)(tp+8);  // f4(x,y)
    float sx, sy;
    { float dx=t0-qA.x, dy=t0-qA.y; sx=dx*dx; sy=dy*dy; }
    { float dx=t1-qA.z, dy=t1-qA.w; float wx=dx*dx, wy=dy*dy; sx=sx+wx; sy=sy+wy; }
    { float dx=t2-qB.x, dy=t2-qB.y; float wx=dx*dx, wy=dy*dy; sx=sx+wx; sy=sy+wy; }
    { float dx=t3-qB.z, dy=t3-qB.w; float wx=dx*dx, wy=dy*dy; sx=sx+wx; sy=sy+wy; }
    { float dx=t4-qC.x, dy=t4-qC.y; float wx=dx*dx, wy=dy*dy; sx=sx+wx; sy=sy+wy; }
    float tx=fmaxf(a0x,sx), ty=fmaxf(a0y,sy);
    a0x=fminf(a0x,sx);      a0y=fminf(a0y,sy);
    a1x=fminf(a1x,tx);      a1y=fminf(a1y,ty);
  }
  // exact 2nd-smallest of union of the two sorted pairs (bitonic split)
  float a1 = fmaxf(fminf(a0x,a1y), fminf(a1x,a0y));

  // bg pairs 25..49 (rows 50..99): packed top-4 insertion network
  float b0x=1e30f,b0y=1e30f, b1x=1e30f,b1y=1e30f;
  float b2x=1e30f,b2y=1e30f, b3x=1e30f,b3y=1e30f;
#pragma unroll 5
  for(int pr=25;pr<50;pr++){
    const float* tp = &ts2[pr*12];
    float4 qA = *(const float4*)(tp);
    float4 qB = *(const float4*)(tp+4);
    float2 qC = *(const float2*)(tp+8);
    float sx, sy;
    { float dx=t0-qA.x, dy=t0-qA.y; sx=dx*dx; sy=dy*dy; }
    { float dx=t1-qA.z, dy=t1-qA.w; float wx=dx*dx, wy=dy*dy; sx=sx+wx; sy=sy+wy; }
    { float dx=t2-qB.x, dy=t2-qB.y; float wx=dx*dx, wy=dy*dy; sx=sx+wx; sy=sy+wy; }
    { float dx=t3-qB.z, dy=t3-qB.w; float wx=dx*dx, wy=dy*dy; sx=sx+wx; sy=sy+wy; }
    { float dx=t4-qC.x, dy=t4-qC.y; float wx=dx*dx, wy=dy*dy; sx=sx+wx; sy=sy+wy; }
    float u0x=fmaxf(b0x,sx), u0y=fmaxf(b0y,sy);
    b0x=fminf(b0x,sx);       b0y=fminf(b0y,sy);
    float u1x=fmaxf(b1x,u0x), u1y=fmaxf(b1y,u0y);
    b1x=fminf(b1x,u0x);       b1y=fminf(b1y,u0y);
    float u2x=fmaxf(b2x,u1x), u2y=fmaxf(b2y,u1y);
    b2x=fminf(b2x,u1x);       b2y=fminf(b2y,u1y);
    b3x=fminf(b3x,u2x);       b3y=fminf(b3y,u2y);
  }
  // exact 4th-smallest of union of two sorted quads (bitonic lower-half merge)
  float l0=fminf(b0x,b3y), l1=fminf(b1x,b2y), l2=fminf(b2x,b1y), l3=fminf(b3x,b0y);
  float b3 = fmaxf(fmaxf(l0,l1), fmaxf(l2,l3));

  // seg <=> 2nd-smallest fg sqrt-dist <= 4th-smallest bg sqrt-dist (fg wins ties)
  bool seg = sqrtf(a1) <= sqrtf(b3);
  __syncthreads();                       // pix reuse fence
  pix[tid*3+0]=seg?ip0:0.f;
  pix[tid*3+1]=seg?ip1:0.f;
  pix[tid*3+2]=seg?ip2:0.f;
  __syncthreads();
  float4* ob4 = (float4*)(out + ((size_t)img*NPIX + (size_t)chunk*256)*3);
  if(tid<192) ob4[tid] = ((float4*)pix)[tid];
}

extern "C" void kernel_launch(void* const* d_in, const int* in_sizes, int n_in,
                              void* d_out, int out_size, void* d_ws, size_t ws_size,
                              hipStream_t stream) {
  const float* in = (const float*)d_in[0];
  float* out = (float*)d_out;
  float* maxpart = (float*)d_ws;                                          // 2304 B
  unsigned long long* key50g = (unsigned long long*)((char*)d_ws + 2304); // 204800 B
  float* ts2g    = (float*)((char*)d_ws + 207104);                        // 76800 B
  float* meanstd = (float*)((char*)d_ws + 283904);                        // 1280 B

  kmax  <<<192,  256, 0, stream>>>(in, maxpart);
  kscore<<<512,  256, 0, stream>>>(in, maxpart, key50g);
  kmerge<<<32,   256, 0, stream>>>(in, key50g, ts2g, meanstd);
  kknn  <<<1152, 256, 0, stream>>>(in, ts2g, meanstd, out);
}